// Round 4
// baseline (1066.850 us; speedup 1.0000x reference)
//
#include <hip/hip_runtime.h>

// Problem constants
#define HH 22
#define WW 22
#define HWN 484
#define NBATCH 64
#define SDIM 8
#define NMAPS (NBATCH*HWN)      // 30976
#define PADW 24
#define PADSZ (PADW*PADW)       // 576

#define LOAD_NB(arr, bb) do { \
    nb[0]=(arr)[(bb)-PADW-1]; nb[1]=(arr)[(bb)-PADW]; nb[2]=(arr)[(bb)-PADW+1]; \
    nb[3]=(arr)[(bb)-1];      nb[4]=(arr)[(bb)];      nb[5]=(arr)[(bb)+1]; \
    nb[6]=(arr)[(bb)+PADW-1]; nb[7]=(arr)[(bb)+PADW]; nb[8]=(arr)[(bb)+PADW+1]; } while(0)

// -------------------------------------------------- conv(1->8) stats pass
__global__ __launch_bounds__(256) void k_stats(const float* __restrict__ src,
    const float* __restrict__ w, const float* __restrict__ b,
    float* __restrict__ Sg, float* __restrict__ Qg)
{
    __shared__ float xin[PADSZ];
    __shared__ float red[16];
    int tid=threadIdx.x;
    for(int q=tid;q<PADSZ;q+=256) xin[q]=0.f;
    float accS[8], accQ[8];
#pragma unroll
    for(int c=0;c<8;++c){ accS[c]=0.f; accQ[c]=0.f; }
    int m0=blockIdx.x*16;
    for(int m=m0;m<m0+16;++m){
        __syncthreads();
        const size_t base=(size_t)m*HWN;
        for(int p=tid;p<HWN;p+=256){
            int i=p/WW, j=p-i*WW;
            xin[(i+1)*PADW+j+1]=src[base+p];
        }
        __syncthreads();
        for(int p=tid;p<HWN;p+=256){
            int i=p/WW, j=p-i*WW, aa=(i+1)*PADW+j+1;
            float nb[9]; LOAD_NB(xin, aa);
#pragma unroll
            for(int c=0;c<8;++c){
                float y=b[c];
#pragma unroll
                for(int t=0;t<9;++t) y=fmaf(w[c*9+t], nb[t], y);
                accS[c]+=y; accQ[c]=fmaf(y,y,accQ[c]);
            }
        }
    }
    __syncthreads();
    if(tid<16) red[tid]=0.f;
    __syncthreads();
    int lane=tid&63;
#pragma unroll
    for(int c=0;c<8;++c){
        float s=accS[c], q=accQ[c];
        for(int o=32;o;o>>=1){ s+=__shfl_down(s,o); q+=__shfl_down(q,o); }
        if(lane==0){ atomicAdd(&red[c],s); atomicAdd(&red[8+c],q); }
    }
    __syncthreads();
    if(tid<8){ atomicAdd(&Sg[tid],red[tid]); atomicAdd(&Qg[tid],red[8+tid]); }
}

// --------------------------------- conv(1->8)+BN+ReLU+conv(8->1) apply pass
__global__ __launch_bounds__(256) void k_convpair(const float* __restrict__ src, float* __restrict__ Ydst,
    const float* __restrict__ w1, const float* __restrict__ b1,
    const float* __restrict__ sc, const float* __restrict__ sh,
    const float* __restrict__ w2, const float* __restrict__ b2,
    float* __restrict__ Sg, float* __restrict__ Qg)
{
    __shared__ float xin[PADSZ];
    __shared__ float z[8*PADSZ];
    __shared__ float red[2];
    int tid=threadIdx.x;
    for(int q=tid;q<PADSZ;q+=256) xin[q]=0.f;
    for(int q=tid;q<8*PADSZ;q+=256) z[q]=0.f;
    float aS=0.f, aQ=0.f;
    float b2v=b2[0];
    int m0=blockIdx.x*16;
    for(int m=m0;m<m0+16;++m){
        __syncthreads();
        const size_t base=(size_t)m*HWN;
        for(int p=tid;p<HWN;p+=256){
            int i=p/WW, j=p-i*WW;
            xin[(i+1)*PADW+j+1]=src[base+p];
        }
        __syncthreads();
        for(int p=tid;p<HWN;p+=256){
            int i=p/WW, j=p-i*WW, aa=(i+1)*PADW+j+1;
            float nb[9]; LOAD_NB(xin, aa);
#pragma unroll
            for(int c=0;c<8;++c){
                float y=b1[c];
#pragma unroll
                for(int t=0;t<9;++t) y=fmaf(w1[c*9+t], nb[t], y);
                y=fmaf(y, sc[c], sh[c]);
                z[c*PADSZ+aa]=y>0.f?y:0.f;
            }
        }
        __syncthreads();
        for(int p=tid;p<HWN;p+=256){
            int i=p/WW, j=p-i*WW, aa=(i+1)*PADW+j+1;
            float y=b2v;
#pragma unroll
            for(int c=0;c<8;++c){
                float nb[9]; int bb=c*PADSZ+aa;
                LOAD_NB(z, bb);
                const float* wp=w2+c*9;
#pragma unroll
                for(int t=0;t<9;++t) y=fmaf(wp[t], nb[t], y);
            }
            Ydst[base+p]=y;
            aS+=y; aQ=fmaf(y,y,aQ);
        }
    }
    __syncthreads();
    if(tid<2) red[tid]=0.f;
    __syncthreads();
    int lane=tid&63;
    for(int o=32;o;o>>=1){ aS+=__shfl_down(aS,o); aQ+=__shfl_down(aQ,o); }
    if(lane==0){ atomicAdd(&red[0],aS); atomicAdd(&red[1],aQ); }
    __syncthreads();
    if(tid==0){ atomicAdd(Sg,red[0]); atomicAdd(Qg,red[1]); }
}

// ----------------------------------------------------------- BN finalize
__global__ void k_fin(const float* __restrict__ S, const float* __restrict__ Q,
                      const float* __restrict__ g, const float* __restrict__ be,
                      float* __restrict__ scale, float* __restrict__ shift, int nc)
{
    int c=threadIdx.x;
    if(c<nc){
        const float invC = 1.f/(float)((size_t)NMAPS*HWN);
        float mean=S[c]*invC;
        float var=fmaf(-mean, mean, Q[c]*invC);
        float scv=g[c]*rsqrtf(var+1e-5f);
        scale[c]=scv;
        shift[c]=fmaf(-mean, scv, be[c]);
    }
}

// ----------------------------- per-map (row) softmax with BN affine, in place
__global__ __launch_bounds__(256) void k_smax(float* __restrict__ Y,
    const float* __restrict__ sc2, const float* __restrict__ sh2)
{
    int w = (blockIdx.x<<2) | (threadIdx.x>>6);
    int lane = threadIdx.x & 63;
    if(w>=NMAPS) return;
    float a=sc2[0], s=sh2[0];
    float* row = Y + (size_t)w*HWN;
    float v[8]; float mx=-1e30f;
#pragma unroll
    for(int k=0;k<8;++k){
        int idx=lane+64*k;
        v[k]=(idx<HWN)? fmaf(row[idx], a, s) : -1e30f;
        mx=fmaxf(mx,v[k]);
    }
    for(int o=32;o;o>>=1) mx=fmaxf(mx,__shfl_xor(mx,o));
    float sum=0.f;
#pragma unroll
    for(int k=0;k<8;++k){ v[k]=__expf(v[k]-mx); sum+=v[k]; }
    for(int o=32;o;o>>=1) sum+=__shfl_xor(sum,o);
    float inv=1.f/sum;
#pragma unroll
    for(int k=0;k<8;++k){
        int idx=lane+64*k;
        if(idx<HWN) row[idx]=v[k]*inv;
    }
}

// -------- column softmax over p + conf + einsum('nphw,npd->ndhw') fused
__global__ __launch_bounds__(128) void k_prop(const float* __restrict__ Y,
    const float* __restrict__ sc4, const float* __restrict__ sh4,
    const float* __restrict__ state, float* __restrict__ prop, float* __restrict__ conf)
{
    int n=blockIdx.x;
    __shared__ float sst[8*HWN];
    int tid=threadIdx.x;
    for(int q=tid;q<8*HWN;q+=128) sst[q]=state[(size_t)n*8*HWN + q];
    __syncthreads();
    int t = blockIdx.y*121 + tid;
    if(tid>=121) return;
    float a=sc4[0], sh=sh4[0];
    const float* col = Y + (size_t)n*HWN*HWN + t;
    float mx=-1e30f;
#pragma unroll 4
    for(int p=0;p<HWN;++p){
        float v=fmaf(col[(size_t)p*HWN], a, sh);
        mx=fmaxf(mx,v);
    }
    float ssum=0.f;
    float acc[8];
#pragma unroll
    for(int d=0;d<8;++d) acc[d]=0.f;
#pragma unroll 2
    for(int p=0;p<HWN;++p){
        float v=fmaf(col[(size_t)p*HWN], a, sh);
        float e=__expf(v-mx);
        ssum+=e;
#pragma unroll
        for(int d=0;d<8;++d) acc[d]=fmaf(e, sst[d*HWN+p], acc[d]);
    }
    float inv=1.f/ssum;
    conf[(size_t)n*HWN+t]=inv;
#pragma unroll
    for(int d=0;d<8;++d) prop[((size_t)n*8+d)*HWN+t]=acc[d]*inv;
}

// ------------------------------------------------ response conv1: 10 -> 64
__global__ __launch_bounds__(256) void k_rp1(const float* __restrict__ prop,
    const float* __restrict__ dimp, const float* __restrict__ conf,
    const float* __restrict__ wf, const float* __restrict__ bfv, float* __restrict__ R1)
{
    int n=blockIdx.x, g=blockIdx.y;
    __shared__ float pin[10*PADSZ];
    int tid=threadIdx.x;
    for(int i=tid;i<10*PADSZ;i+=256) pin[i]=0.f;
    __syncthreads();
    for(int p=tid;p<HWN;p+=256){
        int i=p/WW, j=p-i*WW; int aa=(i+1)*PADW+j+1;
#pragma unroll
        for(int d=0;d<8;++d) pin[d*PADSZ+aa]=prop[((size_t)n*8+d)*HWN+p];
        pin[8*PADSZ+aa]=dimp[(size_t)n*HWN+p];
        pin[9*PADSZ+aa]=conf[(size_t)n*HWN+p];
    }
    __syncthreads();
    const float* wg = wf + (size_t)(g*16)*90;
    for(int p=tid;p<HWN;p+=256){
        int i=p/WW, j=p-i*WW; int aa=(i+1)*PADW+j+1;
        float acc[16];
#pragma unroll
        for(int o=0;o<16;++o) acc[o]=bfv[g*16+o];
#pragma unroll
        for(int c=0;c<10;++c){
            float nb[9]; int bb=c*PADSZ+aa;
            LOAD_NB(pin, bb);
#pragma unroll
            for(int o=0;o<16;++o){
                const float* w=wg+o*90+c*9;
#pragma unroll
                for(int t=0;t<9;++t) acc[o]=fmaf(w[t], nb[t], acc[o]);
            }
        }
#pragma unroll
        for(int o=0;o<16;++o){
            float y=acc[o];
            R1[((size_t)n*64 + g*16+o)*HWN+p]= y>0.f?y:0.f;
        }
    }
}

// ------------------------------------------------ response conv2: 64 -> 32
__global__ __launch_bounds__(512) void k_rp2(const float* __restrict__ R1,
    const float* __restrict__ wf, const float* __restrict__ bfv, float* __restrict__ R2)
{
    int n=blockIdx.x, g=blockIdx.y;     // g: 0..3, 8 out-ch each
    __shared__ float xc[16*PADSZ];
    int tid=threadIdx.x;
    for(int i=tid;i<16*PADSZ;i+=512) xc[i]=0.f;
    int p=tid; bool act = p<HWN;
    int i=p/WW, j=p-i*WW, aa=(i+1)*PADW+j+1;
    float acc[8];
#pragma unroll
    for(int o=0;o<8;++o) acc[o]=0.f;
    for(int k=0;k<4;++k){
        __syncthreads();
        for(int q=tid;q<16*HWN;q+=512){
            int ic=q/HWN, pp=q-ic*HWN;
            int ii=pp/WW, jj=pp-ii*WW;
            xc[ic*PADSZ+(ii+1)*PADW+jj+1]=R1[((size_t)n*64 + k*16+ic)*HWN+pp];
        }
        __syncthreads();
        if(act){
#pragma unroll
            for(int ic=0;ic<16;++ic){
                float nb[9]; int bb=ic*PADSZ+aa;
                LOAD_NB(xc, bb);
#pragma unroll
                for(int o=0;o<8;++o){
                    const float* w = wf + ((size_t)(g*8+o)*64 + k*16+ic)*9;
#pragma unroll
                    for(int t=0;t<9;++t) acc[o]=fmaf(w[t], nb[t], acc[o]);
                }
            }
        }
    }
    if(act){
#pragma unroll
        for(int o=0;o<8;++o){
            float y=acc[o]+bfv[g*8+o];
            R2[((size_t)n*32+g*8+o)*HWN+p]= y>0.f?y:0.f;
        }
    }
}

// ------------------- response conv3: 32 -> 1, sigmoid, + per-n max pools
__global__ __launch_bounds__(512) void k_resp(const float* __restrict__ R2,
    const float* __restrict__ wf, const float* __restrict__ bfv,
    const float* __restrict__ dimp, float* __restrict__ fused,
    float* __restrict__ pool, float* __restrict__ out)
{
    int n=blockIdx.x;
    __shared__ float xc[16*PADSZ];
    __shared__ float redf[8], redd[8];
    int tid=threadIdx.x;
    for(int i=tid;i<16*PADSZ;i+=512) xc[i]=0.f;
    int p=tid; bool act=p<HWN;
    int i=p/WW, j=p-i*WW, aa=(i+1)*PADW+j+1;
    float acc=0.f;
    for(int k=0;k<2;++k){
        __syncthreads();
        for(int q=tid;q<16*HWN;q+=512){
            int ic=q/HWN, pp=q-ic*HWN;
            int ii=pp/WW, jj=pp-ii*WW;
            xc[ic*PADSZ+(ii+1)*PADW+jj+1]=R2[((size_t)n*32+k*16+ic)*HWN+pp];
        }
        __syncthreads();
        if(act){
#pragma unroll
            for(int ic=0;ic<16;++ic){
                float nb[9]; int bb=ic*PADSZ+aa;
                LOAD_NB(xc, bb);
                const float* w=wf+(size_t)(k*16+ic)*9;
#pragma unroll
                for(int t=0;t<9;++t) acc=fmaf(w[t], nb[t], acc);
            }
        }
    }
    float fval=-1e30f, dval=-1e30f;
    if(act){
        float y=acc+bfv[0];
        float s=1.f/(1.f+__expf(-y));
        fused[(size_t)n*HWN+p]=s;
        out[(size_t)n*9*HWN+p]=s;
        fval=s;
        dval=dimp[(size_t)n*HWN+p];
    }
    int lane=tid&63, wid=tid>>6;
    for(int o=32;o;o>>=1){ fval=fmaxf(fval,__shfl_xor(fval,o)); dval=fmaxf(dval,__shfl_xor(dval,o)); }
    if(lane==0){ redf[wid]=fval; redd[wid]=dval; }
    __syncthreads();
    if(tid==0){
        float fm=redf[0], dm=redd[0];
        for(int q=1;q<8;++q){ fm=fmaxf(fm,redf[q]); dm=fmaxf(dm,redd[q]); }
        pool[n*2+0]=dm; pool[n*2+1]=fm;
    }
}

// --------------------------------------------------------------- ConvGRU
__global__ __launch_bounds__(512) void k_gru(const float* __restrict__ dimp,
    const float* __restrict__ fused, const float* __restrict__ pool,
    const float* __restrict__ prop,
    const float* __restrict__ wr, const float* __restrict__ br,
    const float* __restrict__ wu, const float* __restrict__ bu,
    const float* __restrict__ wo, const float* __restrict__ bo,
    float* __restrict__ out)
{
    int n=blockIdx.x;
    __shared__ float sg[12*PADSZ];
    __shared__ float pr[8*PADSZ];
    int tid=threadIdx.x;
    for(int i=tid;i<12*PADSZ;i+=512) sg[i]=0.f;
    for(int i=tid;i<8*PADSZ;i+=512) pr[i]=0.f;
    __syncthreads();
    float p0=pool[n*2+0], p1=pool[n*2+1];
    for(int p=tid;p<HWN;p+=512){
        int i=p/WW, j=p-i*WW, aa=(i+1)*PADW+j+1;
        sg[0*PADSZ+aa]=dimp[(size_t)n*HWN+p];
        sg[1*PADSZ+aa]=fused[(size_t)n*HWN+p];
        sg[2*PADSZ+aa]=p0;
        sg[3*PADSZ+aa]=p1;
#pragma unroll
        for(int d=0;d<8;++d) sg[(4+d)*PADSZ+aa]=prop[((size_t)n*8+d)*HWN+p];
    }
    __syncthreads();
    int p=tid; bool act=p<HWN;
    int i=p/WW, j=p-i*WW, aa=(i+1)*PADW+j+1;
    float upd[8];
    if(act){
        float ua[8], ra[8];
#pragma unroll
        for(int o=0;o<8;++o){ ua[o]=bu[o]; ra[o]=br[o]; }
#pragma unroll
        for(int ic=0;ic<12;++ic){
            float nb[9]; int bb=ic*PADSZ+aa;
            LOAD_NB(sg, bb);
#pragma unroll
            for(int o=0;o<8;++o){
                const float* wup=wu+((size_t)o*12+ic)*9;
                const float* wrp=wr+((size_t)o*12+ic)*9;
#pragma unroll
                for(int t=0;t<9;++t){
                    ua[o]=fmaf(wup[t], nb[t], ua[o]);
                    ra[o]=fmaf(wrp[t], nb[t], ra[o]);
                }
            }
        }
#pragma unroll
        for(int o=0;o<8;++o){
            upd[o]=1.f/(1.f+__expf(-ua[o]));
            float rst=1.f/(1.f+__expf(-ra[o]));
            pr[o*PADSZ+aa]=sg[(4+o)*PADSZ+aa]*rst;
        }
    }
    __syncthreads();
    if(act){
        float oa[8];
#pragma unroll
        for(int o=0;o<8;++o) oa[o]=bo[o];
#pragma unroll
        for(int ic=0;ic<12;++ic){
            const float* srcp = (ic<4)? (sg+ic*PADSZ) : (pr+(ic-4)*PADSZ);
            float nb[9]; int bb=aa;
            LOAD_NB(srcp, bb);
#pragma unroll
            for(int o=0;o<8;++o){
                const float* wop=wo+((size_t)o*12+ic)*9;
#pragma unroll
                for(int t=0;t<9;++t) oa[o]=fmaf(wop[t], nb[t], oa[o]);
            }
        }
#pragma unroll
        for(int o=0;o<8;++o){
            float od=tanhf(oa[o]);
            float ph=sg[(4+o)*PADSZ+aa];
            float sn=ph*(1.f-upd[o])+od*upd[o];
            out[((size_t)n*9+1+o)*HWN+p]=sn;
        }
    }
}

// ===========================================================================
extern "C" void kernel_launch(void* const* d_in, const int* in_sizes, int n_in,
                              void* d_out, int out_size, void* d_ws, size_t ws_size,
                              hipStream_t stream)
{
    (void)in_sizes; (void)n_in; (void)out_size; (void)ws_size;
    float* ws=(float*)d_ws;
    // ws layout (float offsets)
    float* Y     = ws;                       // 14,992,384
    float* PROP  = ws + 14992384;            // 247,808
    float* CONF  = PROP + 247808;            // 30,976
    float* FUSED = CONF + 30976;             // 30,976
    float* POOL  = FUSED + 30976;            // 128
    float* STATS = POOL + 128;               // 36
    float* SCSH  = STATS + 36;               // 36
    float* R1    = ws;                       // alias Y (dead after k_prop)
    float* R2    = ws + 4000000;

    const float* cv    = (const float*)d_in[0];
    const float* state = (const float*)d_in[1];
    const float* dimp  = (const float*)d_in[2];
    float* out = (float*)d_out;

    hipMemsetAsync(STATS, 0, 36*sizeof(float), stream);

    float *S1=STATS,*Q1=STATS+8,*S2=STATS+16,*Q2=STATS+17,*S3=STATS+18,*Q3=STATS+26,*S4=STATS+34,*Q4=STATS+35;
    float *sc1=SCSH,*sh1=SCSH+8,*sc2=SCSH+16,*sh2=SCSH+17,*sc3=SCSH+18,*sh3=SCSH+26,*sc4=SCSH+34,*sh4=SCSH+35;

    const float* cv1_w1=(const float*)d_in[3];  const float* cv1_b1=(const float*)d_in[4];
    const float* cv1_g1=(const float*)d_in[5];  const float* cv1_be1=(const float*)d_in[6];
    const float* cv1_w2=(const float*)d_in[7];  const float* cv1_b2=(const float*)d_in[8];
    const float* cv1_g2=(const float*)d_in[9];  const float* cv1_be2=(const float*)d_in[10];
    const float* cv2_w1=(const float*)d_in[11]; const float* cv2_b1=(const float*)d_in[12];
    const float* cv2_g1=(const float*)d_in[13]; const float* cv2_be1=(const float*)d_in[14];
    const float* cv2_w2=(const float*)d_in[15]; const float* cv2_b2=(const float*)d_in[16];
    const float* cv2_g2=(const float*)d_in[17]; const float* cv2_be2=(const float*)d_in[18];
    const float* rp1_w=(const float*)d_in[19];  const float* rp1_b=(const float*)d_in[20];
    const float* rp2_w=(const float*)d_in[21];  const float* rp2_b=(const float*)d_in[22];
    const float* resp_w=(const float*)d_in[23]; const float* resp_b=(const float*)d_in[24];
    const float* gru_rw=(const float*)d_in[25]; const float* gru_rb=(const float*)d_in[26];
    const float* gru_uw=(const float*)d_in[27]; const float* gru_ub=(const float*)d_in[28];
    const float* gru_ow=(const float*)d_in[29]; const float* gru_ob=(const float*)d_in[30];

    // cv1 stack
    k_stats<<<1936,256,0,stream>>>(cv, cv1_w1, cv1_b1, S1, Q1);
    k_fin<<<1,64,0,stream>>>(S1,Q1,cv1_g1,cv1_be1,sc1,sh1,8);
    k_convpair<<<1936,256,0,stream>>>(cv, Y, cv1_w1, cv1_b1, sc1, sh1, cv1_w2, cv1_b2, S2, Q2);
    k_fin<<<1,64,0,stream>>>(S2,Q2,cv1_g2,cv1_be2,sc2,sh2,1);
    k_smax<<<7744,256,0,stream>>>(Y, sc2, sh2);
    // cv2 stack (in place on Y)
    k_stats<<<1936,256,0,stream>>>(Y, cv2_w1, cv2_b1, S3, Q3);
    k_fin<<<1,64,0,stream>>>(S3,Q3,cv2_g1,cv2_be1,sc3,sh3,8);
    k_convpair<<<1936,256,0,stream>>>(Y, Y, cv2_w1, cv2_b1, sc3, sh3, cv2_w2, cv2_b2, S4, Q4);
    k_fin<<<1,64,0,stream>>>(S4,Q4,cv2_g2,cv2_be2,sc4,sh4,1);
    // column softmax over source positions + conf + propagation einsum
    k_prop<<<dim3(64,4),128,0,stream>>>(Y, sc4, sh4, state, PROP, CONF);
    // response head
    k_rp1<<<dim3(64,4),256,0,stream>>>(PROP, dimp, CONF, rp1_w, rp1_b, R1);
    k_rp2<<<dim3(64,4),512,0,stream>>>(R1, rp2_w, rp2_b, R2);
    k_resp<<<64,512,0,stream>>>(R2, resp_w, resp_b, dimp, FUSED, POOL, out);
    // ConvGRU
    k_gru<<<64,512,0,stream>>>(dimp, FUSED, POOL, PROP,
                               gru_rw, gru_rb, gru_uw, gru_ub, gru_ow, gru_ob, out);
}

// Round 5
// 849.445 us; speedup vs baseline: 1.2559x; 1.2559x over previous
//
#include <hip/hip_runtime.h>

// Problem constants
#define HH 22
#define WW 22
#define HWN 484
#define NBATCH 64
#define SDIM 8
#define NMAPS (NBATCH*HWN)      // 30976
#define PADW 24
#define PADSZ (PADW*PADW)       // 576
#define INVC (1.f/14992384.f)   // 1/(NMAPS*HWN)

// Load a 4x3 (rows x cols) neighborhood starting at LDS offset b0.
#define LD12(A,b0) \
    float t00=(A)[(b0)],        t01=(A)[(b0)+1],        t02=(A)[(b0)+2], \
          t10=(A)[(b0)+PADW],   t11=(A)[(b0)+PADW+1],   t12=(A)[(b0)+PADW+2], \
          t20=(A)[(b0)+2*PADW], t21=(A)[(b0)+2*PADW+1], t22=(A)[(b0)+2*PADW+2], \
          t30=(A)[(b0)+3*PADW], t31=(A)[(b0)+3*PADW+1], t32=(A)[(b0)+3*PADW+2]

#define DOT9(w9,a0,a1,a2,b0_,b1_,b2_,c0,c1,c2,init) \
    fmaf((w9)[0],a0,fmaf((w9)[1],a1,fmaf((w9)[2],a2, \
    fmaf((w9)[3],b0_,fmaf((w9)[4],b1_,fmaf((w9)[5],b2_, \
    fmaf((w9)[6],c0,fmaf((w9)[7],c1,fmaf((w9)[8],c2,(init))))))))))

#define LOAD_NB(arr, bb) do { \
    nb[0]=(arr)[(bb)-PADW-1]; nb[1]=(arr)[(bb)-PADW]; nb[2]=(arr)[(bb)-PADW+1]; \
    nb[3]=(arr)[(bb)-1];      nb[4]=(arr)[(bb)];      nb[5]=(arr)[(bb)+1]; \
    nb[6]=(arr)[(bb)+PADW-1]; nb[7]=(arr)[(bb)+PADW]; nb[8]=(arr)[(bb)+PADW+1]; } while(0)

// -------------------------------------------------- conv(1->8) stats pass
__global__ __launch_bounds__(256) void k_stats(const float* __restrict__ src,
    const float* __restrict__ w, const float* __restrict__ b,
    float* __restrict__ Sg, float* __restrict__ Qg)
{
    __shared__ float xin[PADSZ];
    __shared__ float red[16];
    int tid=threadIdx.x;
    for(int q=tid;q<PADSZ;q+=256) xin[q]=0.f;
    float accS[8], accQ[8];
#pragma unroll
    for(int c=0;c<8;++c){ accS[c]=0.f; accQ[c]=0.f; }
    bool act = tid<242;
    int i2 = tid/22, jj = tid - i2*22;
    int b0 = 2*i2*PADW + jj;            // top-left of 4x3 neighborhood
    int m0=blockIdx.x*16;
    for(int m=m0;m<m0+16;++m){
        __syncthreads();
        const float* sp = src + (size_t)m*HWN;
        { int p=tid;     int i=p/22, j=p-i*22; xin[(i+1)*PADW+j+1]=sp[p]; }
        { int p=tid+256; if(p<HWN){ int i=p/22, j=p-i*22; xin[(i+1)*PADW+j+1]=sp[p]; } }
        __syncthreads();
        if(act){
            LD12(xin,b0);
#pragma unroll
            for(int c=0;c<8;++c){
                const float* w9=w+c*9;
                float bc=b[c];
                float y0=DOT9(w9,t00,t01,t02,t10,t11,t12,t20,t21,t22,bc);
                float y1=DOT9(w9,t10,t11,t12,t20,t21,t22,t30,t31,t32,bc);
                accS[c]+=y0+y1;
                accQ[c]=fmaf(y0,y0,accQ[c]); accQ[c]=fmaf(y1,y1,accQ[c]);
            }
        }
    }
    __syncthreads();
    if(tid<16) red[tid]=0.f;
    __syncthreads();
#pragma unroll
    for(int c=0;c<8;++c){
        float s=accS[c], q=accQ[c];
        for(int o=32;o;o>>=1){ s+=__shfl_down(s,o); q+=__shfl_down(q,o); }
        if((tid&63)==0){ atomicAdd(&red[c],s); atomicAdd(&red[8+c],q); }
    }
    __syncthreads();
    if(tid<8){ atomicAdd(&Sg[tid],red[tid]); atomicAdd(&Qg[tid],red[8+tid]); }
}

// ------ conv(1->8)+BN(in-block finalize)+ReLU+conv(8->1), out stats
__global__ __launch_bounds__(256) void k_convpair(const float* __restrict__ src, float* __restrict__ Ydst,
    const float* __restrict__ w1, const float* __restrict__ b1,
    const float* __restrict__ Sin, const float* __restrict__ Qin,
    const float* __restrict__ g, const float* __restrict__ be,
    const float* __restrict__ w2, const float* __restrict__ b2,
    float* __restrict__ Sg, float* __restrict__ Qg)
{
    __shared__ float xin[PADSZ];
    __shared__ float z[8*PADSZ];
    __shared__ float red[2];
    __shared__ float scs[8], shs[8];
    int tid=threadIdx.x;
    if(tid<8){
        float mean=Sin[tid]*INVC;
        float var=fmaf(-mean,mean,Qin[tid]*INVC);
        float sc=g[tid]*rsqrtf(var+1e-5f);
        scs[tid]=sc; shs[tid]=fmaf(-mean,sc,be[tid]);
    }
    for(int q=tid;q<PADSZ;q+=256) xin[q]=0.f;
    for(int q=tid;q<8*PADSZ;q+=256) z[q]=0.f;
    float aS=0.f, aQ=0.f;
    bool act = tid<242;
    int i2 = tid/22, jj = tid - i2*22;
    int b0 = 2*i2*PADW + jj;
    int zb = b0 + PADW + 1;             // z slot for top pixel
    int ptop = 2*i2*22 + jj;            // flat index of top pixel
    float b2v=b2[0];
    int m0=blockIdx.x*16;
    for(int m=m0;m<m0+16;++m){
        __syncthreads();
        const float* sp = src + (size_t)m*HWN;
        { int p=tid;     int i=p/22, j=p-i*22; xin[(i+1)*PADW+j+1]=sp[p]; }
        { int p=tid+256; if(p<HWN){ int i=p/22, j=p-i*22; xin[(i+1)*PADW+j+1]=sp[p]; } }
        __syncthreads();
        if(act){
            LD12(xin,b0);
#pragma unroll
            for(int c=0;c<8;++c){
                const float* w9=w1+c*9;
                float bc=b1[c], sc=scs[c], sh=shs[c];
                float y0=DOT9(w9,t00,t01,t02,t10,t11,t12,t20,t21,t22,bc);
                float y1=DOT9(w9,t10,t11,t12,t20,t21,t22,t30,t31,t32,bc);
                y0=fmaf(y0,sc,sh); y1=fmaf(y1,sc,sh);
                z[c*PADSZ+zb]      = y0>0.f?y0:0.f;
                z[c*PADSZ+zb+PADW] = y1>0.f?y1:0.f;
            }
        }
        __syncthreads();
        if(act){
            float y0=b2v, y1=b2v;
#pragma unroll
            for(int c=0;c<8;++c){
                const float* w9=w2+c*9;
                int cb=c*PADSZ+b0;
                LD12(z,cb);
                y0=DOT9(w9,t00,t01,t02,t10,t11,t12,t20,t21,t22,y0);
                y1=DOT9(w9,t10,t11,t12,t20,t21,t22,t30,t31,t32,y1);
            }
            float* yp = Ydst + (size_t)m*HWN;
            yp[ptop]=y0; yp[ptop+22]=y1;
            aS+=y0+y1; aQ=fmaf(y0,y0,aQ); aQ=fmaf(y1,y1,aQ);
        }
    }
    __syncthreads();
    if(tid<2) red[tid]=0.f;
    __syncthreads();
    for(int o=32;o;o>>=1){ aS+=__shfl_down(aS,o); aQ+=__shfl_down(aQ,o); }
    if((tid&63)==0){ atomicAdd(&red[0],aS); atomicAdd(&red[1],aQ); }
    __syncthreads();
    if(tid==0){ atomicAdd(Sg,red[0]); atomicAdd(Qg,red[1]); }
}

// ---- BN affine + per-map softmax (in place on Y) fused with conv(1->8) stats
__global__ __launch_bounds__(256) void k_smax_stats(float* __restrict__ Y,
    const float* __restrict__ S2, const float* __restrict__ Q2,
    const float* __restrict__ g2, const float* __restrict__ be2,
    const float* __restrict__ w, const float* __restrict__ b,
    float* __restrict__ Sg, float* __restrict__ Qg)
{
    __shared__ float xin[PADSZ];
    __shared__ float red4[4];
    __shared__ float red[16];
    int tid=threadIdx.x;
    float mean=S2[0]*INVC;
    float var=fmaf(-mean,mean,Q2[0]*INVC);
    float a=g2[0]*rsqrtf(var+1e-5f);
    float sh=fmaf(-mean,a,be2[0]);
    for(int q=tid;q<PADSZ;q+=256) xin[q]=0.f;
    float accS[8], accQ[8];
#pragma unroll
    for(int c=0;c<8;++c){ accS[c]=0.f; accQ[c]=0.f; }
    bool act = tid<242;
    int i2 = tid/22, jj = tid - i2*22;
    int b0 = 2*i2*PADW + jj;
    int p0=tid, p1=tid+256;
    int i0=p0/22, j0=p0-i0*22; int aa0=(i0+1)*PADW+j0+1;
    int aa1=0; if(p1<HWN){ int i1=p1/22, j1=p1-i1*22; aa1=(i1+1)*PADW+j1+1; }
    int m0=blockIdx.x*16;
    for(int m=m0;m<m0+16;++m){
        __syncthreads();                       // xin free from previous conv phase
        float* yp = Y + (size_t)m*HWN;
        // exp without max-shift: input is BN-normalized (|v| < ~10), fp32-safe.
        float e0=__expf(fmaf(yp[p0],a,sh)); xin[aa0]=e0;
        float e1=0.f;
        if(p1<HWN){ e1=__expf(fmaf(yp[p1],a,sh)); xin[aa1]=e1; }
        float part=e0+e1;
        for(int o=32;o;o>>=1) part+=__shfl_down(part,o);
        if((tid&63)==0) red4[tid>>6]=part;
        __syncthreads();                       // red ready; xin stage ordered
        float inv=1.f/(red4[0]+red4[1]+red4[2]+red4[3]);
        yp[p0]=e0*inv;
        if(p1<HWN) yp[p1]=e1*inv;
        if(act){
            LD12(xin,b0);                      // raw exp values; fold inv into dot
#pragma unroll
            for(int c=0;c<8;++c){
                const float* w9=w+c*9;
                float d0=DOT9(w9,t00,t01,t02,t10,t11,t12,t20,t21,t22,0.f);
                float d1=DOT9(w9,t10,t11,t12,t20,t21,t22,t30,t31,t32,0.f);
                float y0=fmaf(inv,d0,b[c]);
                float y1=fmaf(inv,d1,b[c]);
                accS[c]+=y0+y1;
                accQ[c]=fmaf(y0,y0,accQ[c]); accQ[c]=fmaf(y1,y1,accQ[c]);
            }
        }
    }
    __syncthreads();
    if(tid<16) red[tid]=0.f;
    __syncthreads();
#pragma unroll
    for(int c=0;c<8;++c){
        float s=accS[c], q=accQ[c];
        for(int o=32;o;o>>=1){ s+=__shfl_down(s,o); q+=__shfl_down(q,o); }
        if((tid&63)==0){ atomicAdd(&red[c],s); atomicAdd(&red[8+c],q); }
    }
    __syncthreads();
    if(tid<8){ atomicAdd(&Sg[tid],red[tid]); atomicAdd(&Qg[tid],red[8+tid]); }
}

// -------- single-pass column softmax over p + conf + einsum('nphw,npd->ndhw')
__global__ __launch_bounds__(128) void k_prop(const float* __restrict__ Y,
    const float* __restrict__ S4, const float* __restrict__ Q4,
    const float* __restrict__ g4, const float* __restrict__ be4,
    const float* __restrict__ state, float* __restrict__ prop, float* __restrict__ conf)
{
    int n=blockIdx.x;
    __shared__ float sst[8*HWN];
    int tid=threadIdx.x;
    for(int q=tid;q<8*HWN;q+=128) sst[q]=state[(size_t)n*8*HWN + q];
    __syncthreads();
    int t = blockIdx.y*121 + tid;
    if(tid>=121) return;
    float mean=S4[0]*INVC;
    float var=fmaf(-mean,mean,Q4[0]*INVC);
    float a=g4[0]*rsqrtf(var+1e-5f);
    float sh=fmaf(-mean,a,be4[0]);
    const float* col = Y + (size_t)n*HWN*HWN + t;
    float mx=-1e30f, ssum=0.f;
    float acc[8];
#pragma unroll
    for(int d=0;d<8;++d) acc[d]=0.f;
#pragma unroll 4
    for(int p=0;p<HWN;++p){
        float v=fmaf(col[(size_t)p*HWN], a, sh);   // BN output: |v| small, exp safe
        float e=__expf(v);
        mx=fmaxf(mx,v);
        ssum+=e;
#pragma unroll
        for(int d=0;d<8;++d) acc[d]=fmaf(e, sst[d*HWN+p], acc[d]);
    }
    float inv=1.f/ssum;
    conf[(size_t)n*HWN+t]=__expf(mx)*inv;
#pragma unroll
    for(int d=0;d<8;++d) prop[((size_t)n*8+d)*HWN+t]=acc[d]*inv;
}

// ------------------------------------------------ response conv1: 10 -> 64
__global__ __launch_bounds__(256) void k_rp1(const float* __restrict__ prop,
    const float* __restrict__ dimp, const float* __restrict__ conf,
    const float* __restrict__ wf, const float* __restrict__ bfv, float* __restrict__ R1)
{
    int n=blockIdx.x, g=blockIdx.y;
    __shared__ float pin[10*PADSZ];
    int tid=threadIdx.x;
    for(int i=tid;i<10*PADSZ;i+=256) pin[i]=0.f;
    __syncthreads();
    for(int p=tid;p<HWN;p+=256){
        int i=p/WW, j=p-i*WW; int aa=(i+1)*PADW+j+1;
#pragma unroll
        for(int d=0;d<8;++d) pin[d*PADSZ+aa]=prop[((size_t)n*8+d)*HWN+p];
        pin[8*PADSZ+aa]=dimp[(size_t)n*HWN+p];
        pin[9*PADSZ+aa]=conf[(size_t)n*HWN+p];
    }
    __syncthreads();
    const float* wg = wf + (size_t)(g*16)*90;
    for(int p=tid;p<HWN;p+=256){
        int i=p/WW, j=p-i*WW; int aa=(i+1)*PADW+j+1;
        float acc[16];
#pragma unroll
        for(int o=0;o<16;++o) acc[o]=bfv[g*16+o];
#pragma unroll
        for(int c=0;c<10;++c){
            float nb[9]; int bb=c*PADSZ+aa;
            LOAD_NB(pin, bb);
#pragma unroll
            for(int o=0;o<16;++o){
                const float* w=wg+o*90+c*9;
#pragma unroll
                for(int t=0;t<9;++t) acc[o]=fmaf(w[t], nb[t], acc[o]);
            }
        }
#pragma unroll
        for(int o=0;o<16;++o){
            float y=acc[o];
            R1[((size_t)n*64 + g*16+o)*HWN+p]= y>0.f?y:0.f;
        }
    }
}

// ------------------------------------------------ response conv2: 64 -> 32
__global__ __launch_bounds__(512) void k_rp2(const float* __restrict__ R1,
    const float* __restrict__ wf, const float* __restrict__ bfv, float* __restrict__ R2)
{
    int n=blockIdx.x, g=blockIdx.y;
    __shared__ float xc[16*PADSZ];
    int tid=threadIdx.x;
    for(int i=tid;i<16*PADSZ;i+=512) xc[i]=0.f;
    int p=tid; bool act = p<HWN;
    int i=p/WW, j=p-i*WW, aa=(i+1)*PADW+j+1;
    float acc[8];
#pragma unroll
    for(int o=0;o<8;++o) acc[o]=0.f;
    for(int k=0;k<4;++k){
        __syncthreads();
        for(int q=tid;q<16*HWN;q+=512){
            int ic=q/HWN, pp=q-ic*HWN;
            int ii=pp/WW, jj=pp-ii*WW;
            xc[ic*PADSZ+(ii+1)*PADW+jj+1]=R1[((size_t)n*64 + k*16+ic)*HWN+pp];
        }
        __syncthreads();
        if(act){
#pragma unroll
            for(int ic=0;ic<16;++ic){
                float nb[9]; int bb=ic*PADSZ+aa;
                LOAD_NB(xc, bb);
#pragma unroll
                for(int o=0;o<8;++o){
                    const float* w = wf + ((size_t)(g*8+o)*64 + k*16+ic)*9;
#pragma unroll
                    for(int t=0;t<9;++t) acc[o]=fmaf(w[t], nb[t], acc[o]);
                }
            }
        }
    }
    if(act){
#pragma unroll
        for(int o=0;o<8;++o){
            float y=acc[o]+bfv[g*8+o];
            R2[((size_t)n*32+g*8+o)*HWN+p]= y>0.f?y:0.f;
        }
    }
}

// ------------------- response conv3: 32 -> 1, sigmoid, + per-n max pools
__global__ __launch_bounds__(512) void k_resp(const float* __restrict__ R2,
    const float* __restrict__ wf, const float* __restrict__ bfv,
    const float* __restrict__ dimp, float* __restrict__ fused,
    float* __restrict__ pool, float* __restrict__ out)
{
    int n=blockIdx.x;
    __shared__ float xc[16*PADSZ];
    __shared__ float redf[8], redd[8];
    int tid=threadIdx.x;
    for(int i=tid;i<16*PADSZ;i+=512) xc[i]=0.f;
    int p=tid; bool act=p<HWN;
    int i=p/WW, j=p-i*WW, aa=(i+1)*PADW+j+1;
    float acc=0.f;
    for(int k=0;k<2;++k){
        __syncthreads();
        for(int q=tid;q<16*HWN;q+=512){
            int ic=q/HWN, pp=q-ic*HWN;
            int ii=pp/WW, jj=pp-ii*WW;
            xc[ic*PADSZ+(ii+1)*PADW+jj+1]=R2[((size_t)n*32+k*16+ic)*HWN+pp];
        }
        __syncthreads();
        if(act){
#pragma unroll
            for(int ic=0;ic<16;++ic){
                float nb[9]; int bb=ic*PADSZ+aa;
                LOAD_NB(xc, bb);
                const float* w=wf+(size_t)(k*16+ic)*9;
#pragma unroll
                for(int t=0;t<9;++t) acc=fmaf(w[t], nb[t], acc);
            }
        }
    }
    float fval=-1e30f, dval=-1e30f;
    if(act){
        float y=acc+bfv[0];
        float s=1.f/(1.f+__expf(-y));
        fused[(size_t)n*HWN+p]=s;
        out[(size_t)n*9*HWN+p]=s;
        fval=s;
        dval=dimp[(size_t)n*HWN+p];
    }
    int lane=tid&63, wid=tid>>6;
    for(int o=32;o;o>>=1){ fval=fmaxf(fval,__shfl_xor(fval,o)); dval=fmaxf(dval,__shfl_xor(dval,o)); }
    if(lane==0){ redf[wid]=fval; redd[wid]=dval; }
    __syncthreads();
    if(tid==0){
        float fm=redf[0], dm=redd[0];
        for(int q=1;q<8;++q){ fm=fmaxf(fm,redf[q]); dm=fmaxf(dm,redd[q]); }
        pool[n*2+0]=dm; pool[n*2+1]=fm;
    }
}

// --------------------------------------------------------------- ConvGRU
__global__ __launch_bounds__(512) void k_gru(const float* __restrict__ dimp,
    const float* __restrict__ fused, const float* __restrict__ pool,
    const float* __restrict__ prop,
    const float* __restrict__ wr, const float* __restrict__ br,
    const float* __restrict__ wu, const float* __restrict__ bu,
    const float* __restrict__ wo, const float* __restrict__ bo,
    float* __restrict__ out)
{
    int n=blockIdx.x;
    __shared__ float sg[12*PADSZ];
    __shared__ float pr[8*PADSZ];
    int tid=threadIdx.x;
    for(int i=tid;i<12*PADSZ;i+=512) sg[i]=0.f;
    for(int i=tid;i<8*PADSZ;i+=512) pr[i]=0.f;
    __syncthreads();
    float p0=pool[n*2+0], p1=pool[n*2+1];
    for(int p=tid;p<HWN;p+=512){
        int i=p/WW, j=p-i*WW, aa=(i+1)*PADW+j+1;
        sg[0*PADSZ+aa]=dimp[(size_t)n*HWN+p];
        sg[1*PADSZ+aa]=fused[(size_t)n*HWN+p];
        sg[2*PADSZ+aa]=p0;
        sg[3*PADSZ+aa]=p1;
#pragma unroll
        for(int d=0;d<8;++d) sg[(4+d)*PADSZ+aa]=prop[((size_t)n*8+d)*HWN+p];
    }
    __syncthreads();
    int p=tid; bool act=p<HWN;
    int i=p/WW, j=p-i*WW, aa=(i+1)*PADW+j+1;
    float upd[8];
    if(act){
        float ua[8], ra[8];
#pragma unroll
        for(int o=0;o<8;++o){ ua[o]=bu[o]; ra[o]=br[o]; }
#pragma unroll
        for(int ic=0;ic<12;++ic){
            float nb[9]; int bb=ic*PADSZ+aa;
            LOAD_NB(sg, bb);
#pragma unroll
            for(int o=0;o<8;++o){
                const float* wup=wu+((size_t)o*12+ic)*9;
                const float* wrp=wr+((size_t)o*12+ic)*9;
#pragma unroll
                for(int t=0;t<9;++t){
                    ua[o]=fmaf(wup[t], nb[t], ua[o]);
                    ra[o]=fmaf(wrp[t], nb[t], ra[o]);
                }
            }
        }
#pragma unroll
        for(int o=0;o<8;++o){
            upd[o]=1.f/(1.f+__expf(-ua[o]));
            float rst=1.f/(1.f+__expf(-ra[o]));
            pr[o*PADSZ+aa]=sg[(4+o)*PADSZ+aa]*rst;
        }
    }
    __syncthreads();
    if(act){
        float oa[8];
#pragma unroll
        for(int o=0;o<8;++o) oa[o]=bo[o];
#pragma unroll
        for(int ic=0;ic<12;++ic){
            const float* srcp = (ic<4)? (sg+ic*PADSZ) : (pr+(ic-4)*PADSZ);
            float nb[9]; int bb=aa;
            LOAD_NB(srcp, bb);
#pragma unroll
            for(int o=0;o<8;++o){
                const float* wop=wo+((size_t)o*12+ic)*9;
#pragma unroll
                for(int t=0;t<9;++t) oa[o]=fmaf(wop[t], nb[t], oa[o]);
            }
        }
#pragma unroll
        for(int o=0;o<8;++o){
            float od=tanhf(oa[o]);
            float ph=sg[(4+o)*PADSZ+aa];
            float sn=ph*(1.f-upd[o])+od*upd[o];
            out[((size_t)n*9+1+o)*HWN+p]=sn;
        }
    }
}

// ===========================================================================
extern "C" void kernel_launch(void* const* d_in, const int* in_sizes, int n_in,
                              void* d_out, int out_size, void* d_ws, size_t ws_size,
                              hipStream_t stream)
{
    (void)in_sizes; (void)n_in; (void)out_size; (void)ws_size;
    float* ws=(float*)d_ws;
    float* Y     = ws;                       // 14,992,384 floats
    float* PROP  = ws + 14992384;            // 247,808
    float* CONF  = PROP + 247808;            // 30,976
    float* FUSED = CONF + 30976;             // 30,976
    float* POOL  = FUSED + 30976;            // 128
    float* STATS = POOL + 128;               // 36
    float* R1    = ws;                       // alias Y (dead after k_prop)
    float* R2    = ws + 4000000;

    const float* cv    = (const float*)d_in[0];
    const float* state = (const float*)d_in[1];
    const float* dimp  = (const float*)d_in[2];
    float* out = (float*)d_out;

    hipMemsetAsync(STATS, 0, 36*sizeof(float), stream);

    float *S1=STATS,*Q1=STATS+8,*S2=STATS+16,*Q2=STATS+17,*S3=STATS+18,*Q3=STATS+26,*S4=STATS+34,*Q4=STATS+35;

    const float* cv1_w1=(const float*)d_in[3];  const float* cv1_b1=(const float*)d_in[4];
    const float* cv1_g1=(const float*)d_in[5];  const float* cv1_be1=(const float*)d_in[6];
    const float* cv1_w2=(const float*)d_in[7];  const float* cv1_b2=(const float*)d_in[8];
    const float* cv1_g2=(const float*)d_in[9];  const float* cv1_be2=(const float*)d_in[10];
    const float* cv2_w1=(const float*)d_in[11]; const float* cv2_b1=(const float*)d_in[12];
    const float* cv2_g1=(const float*)d_in[13]; const float* cv2_be1=(const float*)d_in[14];
    const float* cv2_w2=(const float*)d_in[15]; const float* cv2_b2=(const float*)d_in[16];
    const float* cv2_g2=(const float*)d_in[17]; const float* cv2_be2=(const float*)d_in[18];
    const float* rp1_w=(const float*)d_in[19];  const float* rp1_b=(const float*)d_in[20];
    const float* rp2_w=(const float*)d_in[21];  const float* rp2_b=(const float*)d_in[22];
    const float* resp_w=(const float*)d_in[23]; const float* resp_b=(const float*)d_in[24];
    const float* gru_rw=(const float*)d_in[25]; const float* gru_rb=(const float*)d_in[26];
    const float* gru_uw=(const float*)d_in[27]; const float* gru_ub=(const float*)d_in[28];
    const float* gru_ow=(const float*)d_in[29]; const float* gru_ob=(const float*)d_in[30];

    // cv1 stack
    k_stats<<<1936,256,0,stream>>>(cv, cv1_w1, cv1_b1, S1, Q1);
    k_convpair<<<1936,256,0,stream>>>(cv, Y, cv1_w1, cv1_b1, S1, Q1, cv1_g1, cv1_be1,
                                      cv1_w2, cv1_b2, S2, Q2);
    // BN2 affine + per-map softmax + cv2 conv1 stats (fused)
    k_smax_stats<<<1936,256,0,stream>>>(Y, S2, Q2, cv1_g2, cv1_be2, cv2_w1, cv2_b1, S3, Q3);
    // cv2 stack (in place on Y)
    k_convpair<<<1936,256,0,stream>>>(Y, Y, cv2_w1, cv2_b1, S3, Q3, cv2_g1, cv2_be1,
                                      cv2_w2, cv2_b2, S4, Q4);
    // single-pass column softmax over p + conf + propagation einsum
    k_prop<<<dim3(64,4),128,0,stream>>>(Y, S4, Q4, cv2_g2, cv2_be2, state, PROP, CONF);
    // response head
    k_rp1<<<dim3(64,4),256,0,stream>>>(PROP, dimp, CONF, rp1_w, rp1_b, R1);
    k_rp2<<<dim3(64,4),512,0,stream>>>(R1, rp2_w, rp2_b, R2);
    k_resp<<<64,512,0,stream>>>(R2, resp_w, resp_b, dimp, FUSED, POOL, out);
    // ConvGRU
    k_gru<<<64,512,0,stream>>>(dimp, FUSED, POOL, PROP,
                               gru_rw, gru_rb, gru_uw, gru_ub, gru_ow, gru_ob, out);
}